// Round 5
// baseline (309.105 us; speedup 1.0000x reference)
//
#include <hip/hip_runtime.h>

// WeatherLSTM round 9 (resubmit; R4 bench was an infra failure, no data).
// Split-phase anti-phase scheduling on one s_barrier.
//  - grid 256 x 512 thr (8 waves), 16 samples/block, 1 block/CU.
//  - R6 limiter: all waves barrier-locked at SAME phase -> act burst
//    (VALU+trans), MFMA burst, and read latency are SEQUENTIAL per step
//    (2490 cy/step vs ~1300 act-issue floor). R8 flags regressed (poll
//    latency). Fix: TWO groups in enforced ANTI-PHASE on the hw barrier.
//  - Group A = waves 0-3 (samples 0-7), B = waves 4-7 (samples 8-15).
//    SIMD s hosts wave s (A) + wave s+4 (B): one wave acts while the
//    other reads+MFMAs, every interval, by construction.
//  - Step k = 2 barrier intervals:
//      interval 2k  : A: M(k)=reads+28 MFMAs   B: ACT(k-1)=acts+writes
//      interval 2k+1: A: ACT(k)                B: M(k)
//  - Each wave: 16 units (u0=wl*16) x both layers, 4 gate-tiles/layer
//    (R8's verified indexing: r = g*64+u0+col, bias over uu=u0+quad*4).
//    28 MFMAs/wave/step (L0: 4x(2h+1x)=12, L1: 4x4=16).
//  - Dup-column trick (R7, verified): B-frag cols 8-15 read col-8's
//    address -> C cols 8-15 duplicate 0-7; lane col<8 acts units
//    {uu,uu+1}, col>=8 acts {uu+2,uu+3} (4 acts/thread via cndmask sel).
//  - Hazards: same-interval LDS touches are disjoint col ranges (A=0-7,
//    B=8-15); all producer->consumer pairs >=1 barrier apart; h0 ring 2,
//    h1 ring 2 (slot math identical to R6, per group).
//  - x table [169][16][8 halves] = 43.3KB (row 168 zeros); LDS 56.6KB.
//  - Acts: weights prescaled log2e (2log2e for g); shared-rcp with fused
//    i*tanh(g) = B*D*(Eg-1)*R. 7 trans + ~20 VALU per act.
//  - MFMA layouts per m89/m91/m120 (verified R2-R8: absmax 4.9e-4).

typedef _Float16 h8 __attribute__((ext_vector_type(8)));
typedef _Float16 h4 __attribute__((ext_vector_type(4)));
typedef _Float16 h2v __attribute__((ext_vector_type(2)));
typedef float f4 __attribute__((ext_vector_type(4)));

#define ROWB 208
#define HBUF (16 * ROWB)              // 3328 B per h slot (16 col slots)
#define XTAB_OFF 0
#define XTAB_BYTES (169 * 256)        // 43264 B (row 168 = zero pad)
#define H0_OFF XTAB_BYTES             // 2 slots
#define H1_OFF (H0_OFF + 2 * HBUF)    // 2 slots
#define SMEM_TOTAL (H1_OFF + 2 * HBUF)   // 56576 B

#define K1F 1.4426950408889634f   // log2(e)
#define K2F 2.8853900817779268f   // 2*log2(e)

__device__ __forceinline__ float exp2_(float x) {
#if __has_builtin(__builtin_amdgcn_exp2f)
  return __builtin_amdgcn_exp2f(x);
#else
  float r; asm("v_exp_f32 %0, %1" : "=v"(r) : "v"(x)); return r;
#endif
}
__device__ __forceinline__ float rcp_(float x) {
#if __has_builtin(__builtin_amdgcn_rcpf)
  return __builtin_amdgcn_rcpf(x);
#else
  float r; asm("v_rcp_f32 %0, %1" : "=v"(r) : "v"(x)); return r;
#endif
}

__device__ __forceinline__ f4 mfma16(h8 a, h8 b, f4 c) {
  return __builtin_amdgcn_mfma_f32_16x16x32_f16(a, b, c, 0, 0, 0);
}

__device__ __forceinline__ h8 load_w8s(const float* __restrict__ p, float sc) {
  h8 r;
#pragma unroll
  for (int j = 0; j < 8; j++) r[j] = (_Float16)(p[j] * sc);
  return r;
}

// a[0]=i,a[1]=f,a[3]=o prescaled K1F; a[2]=g prescaled K2F.
// sigm(i)*tanh(g) = (Eg-1)/(A*C) = B*D*(Eg-1)*R with R=1/(ABCD).
__device__ __forceinline__ void lstm_act(f4 a, float& c, float& h) {
  float Ei = exp2_(-a[0]);
  float Ef = exp2_(-a[1]);
  float Eg = exp2_(a[2]);
  float Eo = exp2_(-a[3]);
  float A = 1.f + Ei, B = 1.f + Ef, C = 1.f + Eg, D = 1.f + Eo;
  float AB = A * B, CD = C * D, BD = B * D;
  float R  = rcp_(AB * CD);
  float fv = (A * CD) * R;               // sigm(f)
  float ig = (BD * (Eg - 1.f)) * R;      // sigm(i)*tanh(g)
  float ov = (AB * C) * R;               // sigm(o)
  c = fv * c + ig;
  float r2 = rcp_(exp2_(c * K2F) + 1.f);
  h = ov * (1.f - 2.f * r2);
}

extern "C" __global__ void __launch_bounds__(512, 2)
weather_lstm_mfma9(const float* __restrict__ x,
                   const float* __restrict__ Wih0, const float* __restrict__ Whh0,
                   const float* __restrict__ bih0, const float* __restrict__ bhh0,
                   const float* __restrict__ Wih1, const float* __restrict__ Whh1,
                   const float* __restrict__ bih1, const float* __restrict__ bhh1,
                   const float* __restrict__ W1, const float* __restrict__ b1,
                   const float* __restrict__ W2, const float* __restrict__ b2,
                   float* __restrict__ out)
{
  __shared__ __align__(16) unsigned char smem[SMEM_TOTAL];
  const int tid  = threadIdx.x;
  const int lane = tid & 63;
  const int w    = tid >> 6;
  const int col  = lane & 15;
  const int quad = lane >> 4;
  const int grp  = w >> 2;            // 0: samples 0-7, 1: samples 8-15
  const int wl   = w & 3;
  const int u0   = wl * 16;           // this wave's 16 units
  const int gcol = (col & 7) + grp * 8;   // real sample (LDS col slot)
  const bool hi  = (col >= 8);        // dup-pair selector
  const int j0   = hi ? 2 : 0;        // act unit sub-offset
  const int uu   = u0 + quad * 4;     // C-frag row base (units uu..uu+3)
  const int sB   = blockIdx.x * 16;

  // ---- weights: 4 gate-tiles per layer (R8-verified indexing) ----
  h8 aW[4][2], aX[4], aI[4][2], aH[4][2];
  f4 bias0[4], bias1[4];
#pragma unroll
  for (int g = 0; g < 4; ++g) {
    const float sc = (g == 2) ? K2F : K1F;
    const int r = g * 64 + u0 + col;
#pragma unroll
    for (int f = 0; f < 2; ++f) {
      aW[g][f] = load_w8s(Whh0 + r * 64 + f * 32 + quad * 8, sc);
      aI[g][f] = load_w8s(Wih1 + r * 64 + f * 32 + quad * 8, sc);
      aH[g][f] = load_w8s(Whh1 + r * 64 + f * 32 + quad * 8, sc);
    }
    h8 xw = {};
    if (quad == 0) {
#pragma unroll
      for (int j = 0; j < 4; ++j) xw[j] = (_Float16)(Wih0[r * 4 + j] * sc);
    }
    aX[g] = xw;
#pragma unroll
    for (int j = 0; j < 4; ++j) {
      bias0[g][j] = (bih0[g * 64 + uu + j] + bhh0[g * 64 + uu + j]) * sc;
      bias1[g][j] = (bih1[g * 64 + uu + j] + bhh1[g * 64 + uu + j]) * sc;
    }
  }

  // ---- zero LDS, build x table ----
  for (int idx = tid; idx < SMEM_TOTAL / 4; idx += 512) ((int*)smem)[idx] = 0;
  __syncthreads();
  for (int idx = tid; idx < 16 * 168; idx += 512) {
    const int c_ = idx / 168, t_ = idx - c_ * 168;
    f4 xv = *(const f4*)(x + ((size_t)(sB + c_) * 168 + t_) * 4);
    h4 xh;
#pragma unroll
    for (int j = 0; j < 4; j++) xh[j] = (_Float16)xv[j];
    *(h4*)(smem + XTAB_OFF + t_ * 256 + c_ * 16) = xh;
  }
  __syncthreads();

  f4 Av[4], Cv[4];                       // persist across the intra-step barrier
  float c0s[2] = {0.f, 0.f}, c1s[2] = {0.f, 0.f}, hl[2] = {0.f, 0.f};
  const int bo = gcol * ROWB + quad * 16;        // B-frag byte offset
  const int wo = gcol * ROWB + (uu + j0) * 2;    // h-write byte offset (4B aligned)
  const unsigned char* xp = smem + XTAB_OFF + gcol * 16;

  auto M = [&](int k) {     // reads + 28 MFMAs for step k (both layers)
    const unsigned char* h0r = smem + H0_OFF + ((k - 1) & 1) * HBUF;  // h0(k-1)
    const unsigned char* h1r = smem + H1_OFF + (k & 1) * HBUF;        // h1(k-2)
    h8 rb0 = *(const h8*)(h0r + bo);
    h8 rb1 = *(const h8*)(h0r + bo + 64);
    h8 rbx = *(const h8*)(xp + k * 256);
    h8 rq0 = *(const h8*)(h1r + bo);
    h8 rq1 = *(const h8*)(h1r + bo + 64);
#pragma unroll
    for (int g = 0; g < 4; ++g) {
      Av[g] = mfma16(aW[g][0], rb0, bias0[g]);
      Cv[g] = mfma16(aI[g][0], rb0, bias1[g]);
      Av[g] = mfma16(aW[g][1], rb1, Av[g]);
      Cv[g] = mfma16(aI[g][1], rb1, Cv[g]);
      Av[g] = mfma16(aX[g], rbx, Av[g]);
      Cv[g] = mfma16(aH[g][0], rq0, Cv[g]);
      Cv[g] = mfma16(aH[g][1], rq1, Cv[g]);
    }
  };

  auto ACT = [&](int k) {   // acts + h writes for step k
    if (k < 168) {          // h0(k)
      h2v hv;
#pragma unroll
      for (int a = 0; a < 2; ++a) {
        f4 G;
#pragma unroll
        for (int g = 0; g < 4; ++g) G[g] = hi ? Av[g][2 + a] : Av[g][a];
        float ho;
        lstm_act(G, c0s[a], ho);
        hv[a] = (_Float16)ho;
      }
      *(h2v*)(smem + H0_OFF + (k & 1) * HBUF + wo) = hv;
    }
    if (k >= 1) {           // h1(k-1)
      h2v hv;
#pragma unroll
      for (int a = 0; a < 2; ++a) {
        f4 G;
#pragma unroll
        for (int g = 0; g < 4; ++g) G[g] = hi ? Cv[g][2 + a] : Cv[g][a];
        lstm_act(G, c1s[a], hl[a]);
        hv[a] = (_Float16)hl[a];
      }
      *(h2v*)(smem + H1_OFF + ((k + 1) & 1) * HBUF + wo) = hv;
    }
  };

  for (int k = 0; k <= 169; ++k) {
    // interval 2k: A computes M(k), B acts on its step k-1
    if (grp == 0) { if (k <= 168) M(k); }
    else          { if (k >= 1)   ACT(k - 1); }
    __syncthreads();
    // interval 2k+1: A acts on step k, B computes M(k)
    if (grp == 0) { if (k <= 168) ACT(k); }
    else          { if (k <= 168) M(k); }
    __syncthreads();
  }

  // ---------- MLP head (x table region dead; overlay) ----------
  float* fh = (float*)smem;              // [16][64] final h2, fp32
  fh[gcol * 64 + uu + j0 + 0] = hl[0];
  fh[gcol * 64 + uu + j0 + 1] = hl[1];
  __syncthreads();

  {
    const int u = tid & 63, g2 = tid >> 6;   // 8 grps x 2 samples
    const float* w1r = W1 + u * 64;
    float* zl = (float*)(smem + 4096);       // [16][64]
#pragma unroll
    for (int rep = 0; rep < 2; ++rep) {
      const int s2 = g2 + rep * 8;
      float za = b1[u];
      const float* f0 = fh + s2 * 64;
      for (int j = 0; j < 64; ++j) za += w1r[j] * f0[j];
      zl[s2 * 64 + u] = fmaxf(za, 0.f);
    }
  }
  __syncthreads();

  if (tid < 192) {
    const float* zl = (const float*)(smem + 4096);
    const int s2 = tid / 12, o = tid - s2 * 12;
    float a = b2[o];
    for (int j = 0; j < 64; ++j) a += W2[o * 64 + j] * zl[s2 * 64 + j];
    out[(sB + s2) * 12 + o] = a;
  }
}

extern "C" void kernel_launch(void* const* d_in, const int* in_sizes, int n_in,
                              void* d_out, int out_size, void* d_ws, size_t ws_size,
                              hipStream_t stream) {
  (void)in_sizes; (void)n_in; (void)d_ws; (void)ws_size; (void)out_size;
  const float* x    = (const float*)d_in[0];
  const float* Wih0 = (const float*)d_in[1];
  const float* Whh0 = (const float*)d_in[2];
  const float* bih0 = (const float*)d_in[3];
  const float* bhh0 = (const float*)d_in[4];
  const float* Wih1 = (const float*)d_in[5];
  const float* Whh1 = (const float*)d_in[6];
  const float* bih1 = (const float*)d_in[7];
  const float* bhh1 = (const float*)d_in[8];
  const float* W1   = (const float*)d_in[9];
  const float* b1   = (const float*)d_in[10];
  const float* W2   = (const float*)d_in[11];
  const float* b2   = (const float*)d_in[12];

  weather_lstm_mfma9<<<dim3(256), dim3(512), 0, stream>>>(
      x, Wih0, Whh0, bih0, bhh0, Wih1, Whh1, bih1, bhh1, W1, b1, W2, b2,
      (float*)d_out);
}

// Round 6
// 242.024 us; speedup vs baseline: 1.2772x; 1.2772x over previous
//
#include <hip/hip_runtime.h>

// WeatherLSTM round 10: LAYER-SPLIT anti-phase on hw barriers, zero added work.
//  - grid 256 x 512 thr (8 waves), 16 samples/block, 1 block/CU.
//  - R6 model (2490cy/step): VALU act-phase 1270 + MFMA phase 475 + dead 750,
//    phases SEQUENTIAL (all waves same phase). R9 failed by ADDING work
//    (dup-cols: 2x MFMA, +cndmasks, 128 VGPR). R8 failed on flag latency.
//    This split is work-conserving: total 112 MFMA + 2048 acts/CU-step, same
//    as R6; per-wave regs ~= R6 (one layer's weights only).
//  - Waves 0-3 = L0 (16 units each: 4 gate-tiles, 12 MFMA, 4 acts/thread);
//    waves 4-7 = L1 (16 MFMA, 4 acts/thread). SIMD s hosts waves s (L0) and
//    s+4 (L1) -> every interval one wave bursts VALU/trans while the other
//    drives ds_read+MFMA.
//  - Schedule (2 barrier intervals per step k, k=0..169):
//      even(k): L0: M0(k)=3 reads+12 MFMA   | L1: ACT1(k-2)+h1-write
//      odd(k) : L0: ACT0(k)+h0-write        | L1: M1(k-1)=4 reads+16 MFMA
//    Deps (all >=1 barrier apart; simulated k=0,1,2,169):
//      M0(k) needs h0(k-1) [odd(k-1)]; ACT1(k-2) needs acc M1(k-2) [odd(k-1)];
//      M1(k-1) needs h0(k-1) [odd(k-1)] + h1(k-2) [even(k), 1 bar before odd];
//      ACT0(k) needs acc M0(k) [even(k)]. Same-interval buffers disjoint:
//      odd: ACT0 writes h0 slot k&1, M1 reads h0 slot (k&1)^1 + h1.
//    Rings depth 2; initial zero slots give h0(-1)=h1(-1)=0.
//  - Accumulators cross exactly ONE barrier in registers (16 VGPR).
//  - Acts take 4 gate scalars directly (no f4 G gather movs).
//  - Per-gate tiles, A-frag r=g*64+u0+col, bias at uu=u0+quad*4, b64 h-writes
//    (all R8-verified indexing, absmax 4.9e-4).
//  - x table [169][16][8 halves] = 43.3KB (L0-only reads); LDS 56.6KB.
//  - Acts: weights prescaled log2e (2log2e for g); shared-rcp with fused
//    i*tanh(g) = B*D*(Eg-1)*R. 7 trans + ~16 VALU per act.
//  - FAILURE CRITERION: if >=200us, divergent 2-barrier pattern is toxic ->
//    revert to R6 + micro-opts next round.

typedef _Float16 h8 __attribute__((ext_vector_type(8)));
typedef _Float16 h4 __attribute__((ext_vector_type(4)));
typedef float f4 __attribute__((ext_vector_type(4)));

#define ROWB 208
#define HBUF (16 * ROWB)              // 3328 B per h slot
#define XTAB_OFF 0
#define XTAB_BYTES (169 * 256)        // 43264 B
#define H0_OFF XTAB_BYTES             // 2 slots
#define H1_OFF (H0_OFF + 2 * HBUF)    // 2 slots
#define SMEM_TOTAL (H1_OFF + 2 * HBUF)   // 56576 B

#define K1F 1.4426950408889634f   // log2(e)
#define K2F 2.8853900817779268f   // 2*log2(e)

__device__ __forceinline__ float exp2_(float x) {
#if __has_builtin(__builtin_amdgcn_exp2f)
  return __builtin_amdgcn_exp2f(x);
#else
  float r; asm("v_exp_f32 %0, %1" : "=v"(r) : "v"(x)); return r;
#endif
}
__device__ __forceinline__ float rcp_(float x) {
#if __has_builtin(__builtin_amdgcn_rcpf)
  return __builtin_amdgcn_rcpf(x);
#else
  float r; asm("v_rcp_f32 %0, %1" : "=v"(r) : "v"(x)); return r;
#endif
}

__device__ __forceinline__ f4 mfma16(h8 a, h8 b, f4 c) {
  return __builtin_amdgcn_mfma_f32_16x16x32_f16(a, b, c, 0, 0, 0);
}

__device__ __forceinline__ h8 load_w8s(const float* __restrict__ p, float sc) {
  h8 r;
#pragma unroll
  for (int j = 0; j < 8; j++) r[j] = (_Float16)(p[j] * sc);
  return r;
}

// gi,gf,go prescaled K1F; gg prescaled K2F.
// sigm(i)*tanh(g) = (Eg-1)/(A*C) = B*D*(Eg-1)*R with R=1/(ABCD).
__device__ __forceinline__ void lstm_act_s(float gi, float gf, float gg, float go,
                                           float& c, float& h) {
  float Ei = exp2_(-gi);
  float Ef = exp2_(-gf);
  float Eg = exp2_(gg);
  float Eo = exp2_(-go);
  float A = 1.f + Ei, B = 1.f + Ef, C = 1.f + Eg, D = 1.f + Eo;
  float AB = A * B, CD = C * D, BD = B * D;
  float R  = rcp_(AB * CD);
  float fv = (A * CD) * R;               // sigm(f)
  float ig = (BD * (Eg - 1.f)) * R;      // sigm(i)*tanh(g)
  float ov = (AB * C) * R;               // sigm(o)
  c = fv * c + ig;
  float r2 = rcp_(exp2_(c * K2F) + 1.f);
  h = ov * (1.f - 2.f * r2);
}

extern "C" __global__ void __launch_bounds__(512, 2)
weather_lstm_mfma10(const float* __restrict__ x,
                    const float* __restrict__ Wih0, const float* __restrict__ Whh0,
                    const float* __restrict__ bih0, const float* __restrict__ bhh0,
                    const float* __restrict__ Wih1, const float* __restrict__ Whh1,
                    const float* __restrict__ bih1, const float* __restrict__ bhh1,
                    const float* __restrict__ W1, const float* __restrict__ b1,
                    const float* __restrict__ W2, const float* __restrict__ b2,
                    float* __restrict__ out)
{
  __shared__ __align__(16) unsigned char smem[SMEM_TOTAL];
  const int tid  = threadIdx.x;
  const int lane = tid & 63;
  const int w    = tid >> 6;          // 0-3 = L0 waves, 4-7 = L1 waves
  const int col  = lane & 15;         // sample (C col) / A-row offset
  const int quad = lane >> 4;         // 0..3
  const bool isL0 = (w < 4);
  const int wl   = w & 3;
  const int u0   = wl * 16;           // this wave's 16 units
  const int uu   = u0 + quad * 4;     // units this thread activates
  const int sB   = blockIdx.x * 16;

  // ---- weights: one layer per wave group, shared register array ----
  // L0: wfrag[2g+f]=Whh0(g,f), wfrag[8+g]=Wih0 x-frag (quad0 only)
  // L1: wfrag[2g+f]=Wih1(g,f), wfrag[8+2g+f]=Whh1(g,f)
  h8 wfrag[16];
  f4 bias[4];
#pragma unroll
  for (int g = 0; g < 4; ++g) {
    const float sc = (g == 2) ? K2F : K1F;
    const int r = g * 64 + u0 + col;
    if (isL0) {
#pragma unroll
      for (int f = 0; f < 2; ++f)
        wfrag[2 * g + f] = load_w8s(Whh0 + r * 64 + f * 32 + quad * 8, sc);
      h8 xw = {};
      if (quad == 0) {
#pragma unroll
        for (int j = 0; j < 4; ++j) xw[j] = (_Float16)(Wih0[r * 4 + j] * sc);
      }
      wfrag[8 + g] = xw;
#pragma unroll
      for (int j = 0; j < 4; ++j)
        bias[g][j] = (bih0[g * 64 + uu + j] + bhh0[g * 64 + uu + j]) * sc;
    } else {
#pragma unroll
      for (int f = 0; f < 2; ++f) {
        wfrag[2 * g + f]     = load_w8s(Wih1 + r * 64 + f * 32 + quad * 8, sc);
        wfrag[8 + 2 * g + f] = load_w8s(Whh1 + r * 64 + f * 32 + quad * 8, sc);
      }
#pragma unroll
      for (int j = 0; j < 4; ++j)
        bias[g][j] = (bih1[g * 64 + uu + j] + bhh1[g * 64 + uu + j]) * sc;
    }
  }

  // ---- zero LDS, build x table ----
  for (int idx = tid; idx < SMEM_TOTAL / 4; idx += 512) ((int*)smem)[idx] = 0;
  __syncthreads();
  for (int idx = tid; idx < 16 * 168; idx += 512) {
    const int c_ = idx / 168, t_ = idx - c_ * 168;
    f4 xv = *(const f4*)(x + ((size_t)(sB + c_) * 168 + t_) * 4);
    h4 xh;
#pragma unroll
    for (int j = 0; j < 4; j++) xh[j] = (_Float16)xv[j];
    *(h4*)(smem + XTAB_OFF + t_ * 256 + c_ * 16) = xh;
  }
  __syncthreads();

  f4 acc[4];                              // crosses exactly one barrier
  float cst[4] = {0.f, 0.f, 0.f, 0.f};
  float hl[4]  = {0.f, 0.f, 0.f, 0.f};    // final h2 (L1 waves)
  const int bo = col * ROWB + quad * 16;  // B-frag byte offset
  const int wo = col * ROWB + uu * 2;     // h-write byte offset (8B aligned)
  const unsigned char* xp = smem + XTAB_OFF + col * 16;

  for (int k = 0; k <= 169; ++k) {
    const int sl = k & 1, slp = sl ^ 1;

    // ---------- even interval ----------
    if (isL0) {
      if (k <= 167) {                     // M0(k): needs h0(k-1) [slot slp]
        const unsigned char* h0r = smem + H0_OFF + slp * HBUF;
        h8 b0  = *(const h8*)(h0r + bo);
        h8 b1v = *(const h8*)(h0r + bo + 64);
        h8 bx  = *(const h8*)(xp + k * 256);
#pragma unroll
        for (int g = 0; g < 4; ++g) acc[g] = mfma16(wfrag[2 * g], b0, bias[g]);
#pragma unroll
        for (int g = 0; g < 4; ++g) acc[g] = mfma16(wfrag[2 * g + 1], b1v, acc[g]);
#pragma unroll
        for (int g = 0; g < 4; ++g) acc[g] = mfma16(wfrag[8 + g], bx, acc[g]);
      }
    } else {
      if (k >= 2) {                       // ACT1(k-2): acc from M1(k-2) [odd(k-1)]
        h4 hv;
#pragma unroll
        for (int a = 0; a < 4; ++a) {
          float ho;
          lstm_act_s(acc[0][a], acc[1][a], acc[2][a], acc[3][a], cst[a], ho);
          hl[a] = ho;
          hv[a] = (_Float16)ho;
        }
        *(h4*)(smem + H1_OFF + sl * HBUF + wo) = hv;   // h1(k-2), slot (k-2)&1=sl
      }
    }
    __syncthreads();

    // ---------- odd interval ----------
    if (isL0) {
      if (k <= 167) {                     // ACT0(k): acc from M0(k) [even(k)]
        h4 hv;
#pragma unroll
        for (int a = 0; a < 4; ++a) {
          float ho;
          lstm_act_s(acc[0][a], acc[1][a], acc[2][a], acc[3][a], cst[a], ho);
          hv[a] = (_Float16)ho;
        }
        *(h4*)(smem + H0_OFF + sl * HBUF + wo) = hv;   // h0(k), slot sl
      }
    } else {
      if (k >= 1 && k <= 168) {           // M1(k-1): h0(k-1) [slp], h1(k-2) [sl]
        const unsigned char* h0r = smem + H0_OFF + slp * HBUF;
        const unsigned char* h1r = smem + H1_OFF + sl * HBUF;
        h8 b0  = *(const h8*)(h0r + bo);
        h8 b1v = *(const h8*)(h0r + bo + 64);
        h8 q0  = *(const h8*)(h1r + bo);
        h8 q1  = *(const h8*)(h1r + bo + 64);
#pragma unroll
        for (int g = 0; g < 4; ++g) acc[g] = mfma16(wfrag[2 * g], b0, bias[g]);
#pragma unroll
        for (int g = 0; g < 4; ++g) acc[g] = mfma16(wfrag[2 * g + 1], b1v, acc[g]);
#pragma unroll
        for (int g = 0; g < 4; ++g) acc[g] = mfma16(wfrag[8 + 2 * g], q0, acc[g]);
#pragma unroll
        for (int g = 0; g < 4; ++g) acc[g] = mfma16(wfrag[9 + 2 * g], q1, acc[g]);
      }
    }
    __syncthreads();
  }

  // ---------- MLP head (x table region dead; overlay) ----------
  float* fh = (float*)smem;              // [16][64] final h2, fp32
  if (!isL0) {
    f4 hv; hv[0] = hl[0]; hv[1] = hl[1]; hv[2] = hl[2]; hv[3] = hl[3];
    *(f4*)(fh + col * 64 + uu) = hv;
  }
  __syncthreads();

  {
    const int u = tid & 63, g2 = tid >> 6;   // 8 grps x 2 samples
    const float* w1r = W1 + u * 64;
    float* zl = (float*)(smem + 4096);       // [16][64]
#pragma unroll
    for (int rep = 0; rep < 2; ++rep) {
      const int s2 = g2 + rep * 8;
      float za = b1[u];
      const float* f0 = fh + s2 * 64;
      for (int j = 0; j < 64; ++j) za += w1r[j] * f0[j];
      zl[s2 * 64 + u] = fmaxf(za, 0.f);
    }
  }
  __syncthreads();

  if (tid < 192) {
    const float* zl = (const float*)(smem + 4096);
    const int s2 = tid / 12, o = tid - s2 * 12;
    float a = b2[o];
    for (int j = 0; j < 64; ++j) a += W2[o * 64 + j] * zl[s2 * 64 + j];
    out[(sB + s2) * 12 + o] = a;
  }
}

extern "C" void kernel_launch(void* const* d_in, const int* in_sizes, int n_in,
                              void* d_out, int out_size, void* d_ws, size_t ws_size,
                              hipStream_t stream) {
  (void)in_sizes; (void)n_in; (void)d_ws; (void)ws_size; (void)out_size;
  const float* x    = (const float*)d_in[0];
  const float* Wih0 = (const float*)d_in[1];
  const float* Whh0 = (const float*)d_in[2];
  const float* bih0 = (const float*)d_in[3];
  const float* bhh0 = (const float*)d_in[4];
  const float* Wih1 = (const float*)d_in[5];
  const float* Whh1 = (const float*)d_in[6];
  const float* bih1 = (const float*)d_in[7];
  const float* bhh1 = (const float*)d_in[8];
  const float* W1   = (const float*)d_in[9];
  const float* b1   = (const float*)d_in[10];
  const float* W2   = (const float*)d_in[11];
  const float* b2   = (const float*)d_in[12];

  weather_lstm_mfma10<<<dim3(256), dim3(512), 0, stream>>>(
      x, Wih0, Whh0, bih0, bhh0, Wih1, Whh1, bih1, bhh1, W1, b1, W2, b2,
      (float*)d_out);
}

// Round 7
// 238.894 us; speedup vs baseline: 1.2939x; 1.0131x over previous
//
#include <hip/hip_runtime.h>

// WeatherLSTM round 12: R10 layer-split anti-phase with MAPPING-ROBUST roles
// + register x-prefetch (x-table removed).
//  - R10 post-mortem: 2648cy/step = R6(2490) + 1 barrier(160) -> overlap NEVER
//    engaged. Cycle model (closes to 2490): VALU 1270 (incl 896 trans@16cy) +
//    MFMA 475 (17cy/instr; explains R7: 2x MFMA = +475 = +37us) + barrier 160
//    + slack. Phases are pipe-exclusive per SIMD; overlapping MFMA under VALU
//    is worth ~30%.
//  - Hypothesis: wave->SIMD mapping may be PAIRWISE {2s,2s+1}, not w%4; R10's
//    w<4 split then put two SAME-role waves per SIMD -> no overlap possible.
//  - Fix: role = (w ^ (w>>2)) & 1 -- differs within {2s,2s+1} AND {s,s+4}:
//    each SIMD hosts one L0-wave + one L1-wave under EITHER mapping.
//    L0 group = {0,2,5,7}, L1 = {1,3,4,6}; rank wl = (w+adj)>>1 covers
//    u0 = wl*16 for 4 waves per role.
//  - Schedule (identical to R10, 2 barrier intervals per step k, k=0..169):
//      even(k): L0: M0(k)=2 ds_reads+12 MFMA | L1: ACT1(k-2)+h1-write
//      odd(k) : L0: ACT0(k)+h0-write         | L1: M1(k-1)=4 reads+16 MFMA
//    All producer->consumer pairs >=1 barrier apart (verified R10, passed).
//  - x-table ELIMINATED: L0 waves keep x(k) in f4 regs; quad0 lanes prefetch
//    x(k+1) (16B global, L1/L2-resident) one interval ahead; cvt to h8 at use.
//    Saves table-build prologue + 1 LDS read/step; LDS 56.6KB -> 13.3KB.
//  - Acts: weights prescaled log2e (2log2e for g); shared-rcp with fused
//    i*tanh(g) = B*D*(Eg-1)*R. 7 trans + ~21 VALU per act (trans-minimal).
//  - MFMA layouts per m89/m91/m120 (verified R2-R10: absmax 4.9e-4).

typedef _Float16 h8 __attribute__((ext_vector_type(8)));
typedef _Float16 h4 __attribute__((ext_vector_type(4)));
typedef float f4 __attribute__((ext_vector_type(4)));

#define ROWB 208
#define HBUF (16 * ROWB)              // 3328 B per h slot
#define H0_OFF 0                      // 2 slots
#define H1_OFF (2 * HBUF)             // 2 slots
#define SMEM_TOTAL (4 * HBUF)         // 13312 B

#define K1F 1.4426950408889634f   // log2(e)
#define K2F 2.8853900817779268f   // 2*log2(e)

__device__ __forceinline__ float exp2_(float x) {
#if __has_builtin(__builtin_amdgcn_exp2f)
  return __builtin_amdgcn_exp2f(x);
#else
  float r; asm("v_exp_f32 %0, %1" : "=v"(r) : "v"(x)); return r;
#endif
}
__device__ __forceinline__ float rcp_(float x) {
#if __has_builtin(__builtin_amdgcn_rcpf)
  return __builtin_amdgcn_rcpf(x);
#else
  float r; asm("v_rcp_f32 %0, %1" : "=v"(r) : "v"(x)); return r;
#endif
}

__device__ __forceinline__ f4 mfma16(h8 a, h8 b, f4 c) {
  return __builtin_amdgcn_mfma_f32_16x16x32_f16(a, b, c, 0, 0, 0);
}

__device__ __forceinline__ h8 load_w8s(const float* __restrict__ p, float sc) {
  h8 r;
#pragma unroll
  for (int j = 0; j < 8; j++) r[j] = (_Float16)(p[j] * sc);
  return r;
}

// gi,gf,go prescaled K1F; gg prescaled K2F.
// sigm(i)*tanh(g) = (Eg-1)/(A*C) = B*D*(Eg-1)*R with R=1/(ABCD).
__device__ __forceinline__ void lstm_act_s(float gi, float gf, float gg, float go,
                                           float& c, float& h) {
  float Ei = exp2_(-gi);
  float Ef = exp2_(-gf);
  float Eg = exp2_(gg);
  float Eo = exp2_(-go);
  float A = 1.f + Ei, B = 1.f + Ef, C = 1.f + Eg, D = 1.f + Eo;
  float AB = A * B, CD = C * D, BD = B * D;
  float R  = rcp_(AB * CD);
  float fv = (A * CD) * R;               // sigm(f)
  float ig = (BD * (Eg - 1.f)) * R;      // sigm(i)*tanh(g)
  float ov = (AB * C) * R;               // sigm(o)
  c = fv * c + ig;
  float r2 = rcp_(exp2_(c * K2F) + 1.f);
  h = ov * (1.f - 2.f * r2);
}

extern "C" __global__ void __launch_bounds__(512, 2)
weather_lstm_mfma12(const float* __restrict__ x,
                    const float* __restrict__ Wih0, const float* __restrict__ Whh0,
                    const float* __restrict__ bih0, const float* __restrict__ bhh0,
                    const float* __restrict__ Wih1, const float* __restrict__ Whh1,
                    const float* __restrict__ bih1, const float* __restrict__ bhh1,
                    const float* __restrict__ W1, const float* __restrict__ b1,
                    const float* __restrict__ W2, const float* __restrict__ b2,
                    float* __restrict__ out)
{
  __shared__ __align__(16) unsigned char smem[SMEM_TOTAL];
  const int tid  = threadIdx.x;
  const int lane = tid & 63;
  const int w    = tid >> 6;
  const int col  = lane & 15;         // sample (C col) / A-row offset
  const int quad = lane >> 4;         // 0..3
  // ---- mapping-robust role: differs within {2s,2s+1} AND {s,s+4} ----
  const int role = (w ^ (w >> 2)) & 1;          // 0 = L0, 1 = L1
  const bool isL0 = (role == 0);
  const int adj  = (w >= 4) ? ((w & 1) ? -1 : 1) : 0;
  const int wl   = (w + adj) >> 1;              // rank within role group, 0..3
  const int u0   = wl * 16;           // this wave's 16 units
  const int uu   = u0 + quad * 4;     // units this thread activates
  const int sB   = blockIdx.x * 16;

  // ---- weights: one layer per wave group ----
  // L0: wfrag[2g+f]=Whh0(g,f), wfrag[8+g]=Wih0 x-frag (quad0 only)
  // L1: wfrag[2g+f]=Wih1(g,f), wfrag[8+2g+f]=Whh1(g,f)
  h8 wfrag[16];
  f4 bias[4];
#pragma unroll
  for (int g = 0; g < 4; ++g) {
    const float sc = (g == 2) ? K2F : K1F;
    const int r = g * 64 + u0 + col;
    if (isL0) {
#pragma unroll
      for (int f = 0; f < 2; ++f)
        wfrag[2 * g + f] = load_w8s(Whh0 + r * 64 + f * 32 + quad * 8, sc);
      h8 xw = {};
      if (quad == 0) {
#pragma unroll
        for (int j = 0; j < 4; ++j) xw[j] = (_Float16)(Wih0[r * 4 + j] * sc);
      }
      wfrag[8 + g] = xw;
#pragma unroll
      for (int j = 0; j < 4; ++j)
        bias[g][j] = (bih0[g * 64 + uu + j] + bhh0[g * 64 + uu + j]) * sc;
    } else {
#pragma unroll
      for (int f = 0; f < 2; ++f) {
        wfrag[2 * g + f]     = load_w8s(Wih1 + r * 64 + f * 32 + quad * 8, sc);
        wfrag[8 + 2 * g + f] = load_w8s(Whh1 + r * 64 + f * 32 + quad * 8, sc);
      }
#pragma unroll
      for (int j = 0; j < 4; ++j)
        bias[g][j] = (bih1[g * 64 + uu + j] + bhh1[g * 64 + uu + j]) * sc;
    }
  }

  // ---- zero h rings (13.3KB) ----
  for (int idx = tid; idx < SMEM_TOTAL / 4; idx += 512) ((int*)smem)[idx] = 0;
  __syncthreads();

  // ---- x prefetch registers (L0 waves, quad0 lanes) ----
  f4 xc = {};
  if (isL0 && quad == 0)
    xc = *(const f4*)(x + ((size_t)(sB + col) * 168 + 0) * 4);

  f4 acc[4];                              // crosses exactly one barrier
  float cst[4] = {0.f, 0.f, 0.f, 0.f};
  float hl[4]  = {0.f, 0.f, 0.f, 0.f};    // final h2 (L1 waves)
  const int bo = col * ROWB + quad * 16;  // B-frag byte offset
  const int wo = col * ROWB + uu * 2;     // h-write byte offset (8B aligned)

  for (int k = 0; k <= 169; ++k) {
    const int sl = k & 1, slp = sl ^ 1;

    // ---------- even interval ----------
    if (isL0) {
      if (k <= 167) {                     // M0(k): needs h0(k-1) [slot slp]
        const unsigned char* h0r = smem + H0_OFF + slp * HBUF;
        h8 b0  = *(const h8*)(h0r + bo);
        h8 b1v = *(const h8*)(h0r + bo + 64);
        h8 bx = {};
        if (quad == 0) {
#pragma unroll
          for (int j = 0; j < 4; ++j) bx[j] = (_Float16)xc[j];
        }
        // prefetch x(k+1) (use is one full interval later)
        {
          const int kn = (k < 167) ? k + 1 : k;
          f4 xn = xc;
          if (quad == 0)
            xn = *(const f4*)(x + ((size_t)(sB + col) * 168 + kn) * 4);
          xc = xn;
        }
#pragma unroll
        for (int g = 0; g < 4; ++g) acc[g] = mfma16(wfrag[2 * g], b0, bias[g]);
#pragma unroll
        for (int g = 0; g < 4; ++g) acc[g] = mfma16(wfrag[2 * g + 1], b1v, acc[g]);
#pragma unroll
        for (int g = 0; g < 4; ++g) acc[g] = mfma16(wfrag[8 + g], bx, acc[g]);
      }
    } else {
      if (k >= 2) {                       // ACT1(k-2): acc from M1(k-2) [odd(k-1)]
        h4 hv;
#pragma unroll
        for (int a = 0; a < 4; ++a) {
          float ho;
          lstm_act_s(acc[0][a], acc[1][a], acc[2][a], acc[3][a], cst[a], ho);
          hl[a] = ho;
          hv[a] = (_Float16)ho;
        }
        *(h4*)(smem + H1_OFF + sl * HBUF + wo) = hv;   // h1(k-2), slot (k-2)&1=sl
      }
    }
    __syncthreads();

    // ---------- odd interval ----------
    if (isL0) {
      if (k <= 167) {                     // ACT0(k): acc from M0(k) [even(k)]
        h4 hv;
#pragma unroll
        for (int a = 0; a < 4; ++a) {
          float ho;
          lstm_act_s(acc[0][a], acc[1][a], acc[2][a], acc[3][a], cst[a], ho);
          hv[a] = (_Float16)ho;
        }
        *(h4*)(smem + H0_OFF + sl * HBUF + wo) = hv;   // h0(k), slot sl
      }
    } else {
      if (k >= 1 && k <= 168) {           // M1(k-1): h0(k-1) [slp], h1(k-2) [sl]
        const unsigned char* h0r = smem + H0_OFF + slp * HBUF;
        const unsigned char* h1r = smem + H1_OFF + sl * HBUF;
        h8 b0  = *(const h8*)(h0r + bo);
        h8 b1v = *(const h8*)(h0r + bo + 64);
        h8 q0  = *(const h8*)(h1r + bo);
        h8 q1  = *(const h8*)(h1r + bo + 64);
#pragma unroll
        for (int g = 0; g < 4; ++g) acc[g] = mfma16(wfrag[2 * g], b0, bias[g]);
#pragma unroll
        for (int g = 0; g < 4; ++g) acc[g] = mfma16(wfrag[2 * g + 1], b1v, acc[g]);
#pragma unroll
        for (int g = 0; g < 4; ++g) acc[g] = mfma16(wfrag[8 + 2 * g], q0, acc[g]);
#pragma unroll
        for (int g = 0; g < 4; ++g) acc[g] = mfma16(wfrag[9 + 2 * g], q1, acc[g]);
      }
    }
    __syncthreads();
  }

  // ---------- MLP head (h rings dead; overlay) ----------
  float* fh = (float*)smem;              // [16][64] final h2, fp32
  if (!isL0) {
    f4 hv; hv[0] = hl[0]; hv[1] = hl[1]; hv[2] = hl[2]; hv[3] = hl[3];
    *(f4*)(fh + col * 64 + uu) = hv;
  }
  __syncthreads();

  {
    const int u = tid & 63, g2 = tid >> 6;   // 8 grps x 2 samples
    const float* w1r = W1 + u * 64;
    float* zl = (float*)(smem + 4096);       // [16][64]
#pragma unroll
    for (int rep = 0; rep < 2; ++rep) {
      const int s2 = g2 + rep * 8;
      float za = b1[u];
      const float* f0 = fh + s2 * 64;
      for (int j = 0; j < 64; ++j) za += w1r[j] * f0[j];
      zl[s2 * 64 + u] = fmaxf(za, 0.f);
    }
  }
  __syncthreads();

  if (tid < 192) {
    const float* zl = (const float*)(smem + 4096);
    const int s2 = tid / 12, o = tid - s2 * 12;
    float a = b2[o];
    for (int j = 0; j < 64; ++j) a += W2[o * 64 + j] * zl[s2 * 64 + j];
    out[(sB + s2) * 12 + o] = a;
  }
}

extern "C" void kernel_launch(void* const* d_in, const int* in_sizes, int n_in,
                              void* d_out, int out_size, void* d_ws, size_t ws_size,
                              hipStream_t stream) {
  (void)in_sizes; (void)n_in; (void)d_ws; (void)ws_size; (void)out_size;
  const float* x    = (const float*)d_in[0];
  const float* Wih0 = (const float*)d_in[1];
  const float* Whh0 = (const float*)d_in[2];
  const float* bih0 = (const float*)d_in[3];
  const float* bhh0 = (const float*)d_in[4];
  const float* Wih1 = (const float*)d_in[5];
  const float* Whh1 = (const float*)d_in[6];
  const float* bih1 = (const float*)d_in[7];
  const float* bhh1 = (const float*)d_in[8];
  const float* W1   = (const float*)d_in[9];
  const float* b1   = (const float*)d_in[10];
  const float* W2   = (const float*)d_in[11];
  const float* b2   = (const float*)d_in[12];

  weather_lstm_mfma12<<<dim3(256), dim3(512), 0, stream>>>(
      x, Wih0, Whh0, bih0, bhh0, Wih1, Whh1, bih1, bhh1, W1, b1, W2, b2,
      (float*)d_out);
}

// Round 8
// 237.813 us; speedup vs baseline: 1.2998x; 1.0045x over previous
//
#include <hip/hip_runtime.h>

// WeatherLSTM round 13: 4 FAT WAVES (256 thr), both layers per wave, 1 barrier.
//  - Post-mortem R10/R12: cross-wave anti-phase overlap NEVER engages (triply
//    falsified, incl. mapping-robust role split) -> step ~= serial sum of
//    phases + barriers, regardless of role assignment. Abandon cross-wave
//    overlap; rely on WITHIN-WAVE ILP only.
//  - Only move that ever won: R5->R6 fatter waves (16->8 waves: 225->176us).
//    Extrapolate: 4 waves x 64 lanes, each wave owns 16 units x BOTH layers
//    (4 gate-tiles/layer), 28 MFMAs + 8 independent act chains per thread-step
//    (4 L0 + 4 L1) -> deep VALU/trans ILP inside one wave, no cross-wave dep.
//  - Per-CU issue work identical to R6 (112 MFMA, 2048 acts, same trans);
//    per-wave overhead & redundant LDS reads HALVED again (16 b128 reads/step
//    vs R6's 40); barrier convoy 8->4 waves; 1 block/CU, 1 wave/SIMD.
//  - R6 step scheme (verified): iter k reads {h0(k-1) slot kbn, h1(k-2) slot
//    kb}, computes L0(k) + L1(k-1), writes {h0(k) slot kb, h1(k-1) slot kbn},
//    ONE barrier. Acts guarded (L0: k<168, L1: k>=1); M computed every iter
//    (edge garbage discarded; inputs are zeroed slots -> no NaN risk).
//  - x-table eliminated (R12, verified): quad0 lanes keep x(k) in f4 regs,
//    prefetch x(k+1) each iter (L2-resident). LDS = h rings only, 13.3KB.
//  - VGPR ~220 (wfrags 112 + biases 32 + acc 32 + state/misc) -> fine at
//    1 wave/SIMD; __launch_bounds__(256,1); gfx950 spills only past ~450.
//  - Acts: weights prescaled log2e (2log2e for g); shared-rcp with fused
//    i*tanh(g) = B*D*(Eg-1)*R. 7 trans + ~21 VALU per act.
//  - MFMA layouts per m89/m91/m120 (verified R2-R12: absmax 4.9e-4).
//  - FAILURE CRITERION: >=170us -> fat-wave direction exhausted; next round
//    reverts to R6 structure + batched-rcp trans cut.

typedef _Float16 h8 __attribute__((ext_vector_type(8)));
typedef _Float16 h4 __attribute__((ext_vector_type(4)));
typedef float f4 __attribute__((ext_vector_type(4)));

#define ROWB 208
#define HBUF (16 * ROWB)              // 3328 B per h slot
#define H0_OFF 0                      // 2 slots
#define H1_OFF (2 * HBUF)             // 2 slots
#define SMEM_TOTAL (4 * HBUF)         // 13312 B

#define K1F 1.4426950408889634f   // log2(e)
#define K2F 2.8853900817779268f   // 2*log2(e)

__device__ __forceinline__ float exp2_(float x) {
#if __has_builtin(__builtin_amdgcn_exp2f)
  return __builtin_amdgcn_exp2f(x);
#else
  float r; asm("v_exp_f32 %0, %1" : "=v"(r) : "v"(x)); return r;
#endif
}
__device__ __forceinline__ float rcp_(float x) {
#if __has_builtin(__builtin_amdgcn_rcpf)
  return __builtin_amdgcn_rcpf(x);
#else
  float r; asm("v_rcp_f32 %0, %1" : "=v"(r) : "v"(x)); return r;
#endif
}

__device__ __forceinline__ f4 mfma16(h8 a, h8 b, f4 c) {
  return __builtin_amdgcn_mfma_f32_16x16x32_f16(a, b, c, 0, 0, 0);
}

__device__ __forceinline__ h8 load_w8s(const float* __restrict__ p, float sc) {
  h8 r;
#pragma unroll
  for (int j = 0; j < 8; j++) r[j] = (_Float16)(p[j] * sc);
  return r;
}

// gi,gf,go prescaled K1F; gg prescaled K2F.
// sigm(i)*tanh(g) = (Eg-1)/(A*C) = B*D*(Eg-1)*R with R=1/(ABCD).
__device__ __forceinline__ void lstm_act_s(float gi, float gf, float gg, float go,
                                           float& c, float& h) {
  float Ei = exp2_(-gi);
  float Ef = exp2_(-gf);
  float Eg = exp2_(gg);
  float Eo = exp2_(-go);
  float A = 1.f + Ei, B = 1.f + Ef, C = 1.f + Eg, D = 1.f + Eo;
  float AB = A * B, CD = C * D, BD = B * D;
  float R  = rcp_(AB * CD);
  float fv = (A * CD) * R;               // sigm(f)
  float ig = (BD * (Eg - 1.f)) * R;      // sigm(i)*tanh(g)
  float ov = (AB * C) * R;               // sigm(o)
  c = fv * c + ig;
  float r2 = rcp_(exp2_(c * K2F) + 1.f);
  h = ov * (1.f - 2.f * r2);
}

extern "C" __global__ void __launch_bounds__(256, 1)
weather_lstm_mfma13(const float* __restrict__ x,
                    const float* __restrict__ Wih0, const float* __restrict__ Whh0,
                    const float* __restrict__ bih0, const float* __restrict__ bhh0,
                    const float* __restrict__ Wih1, const float* __restrict__ Whh1,
                    const float* __restrict__ bih1, const float* __restrict__ bhh1,
                    const float* __restrict__ W1, const float* __restrict__ b1,
                    const float* __restrict__ W2, const float* __restrict__ b2,
                    float* __restrict__ out)
{
  __shared__ __align__(16) unsigned char smem[SMEM_TOTAL];
  const int tid  = threadIdx.x;
  const int lane = tid & 63;
  const int w    = tid >> 6;          // wave 0..3 -> units w*16..w*16+15
  const int col  = lane & 15;         // sample (C col) / A-row offset
  const int quad = lane >> 4;         // 0..3
  const int u0   = w * 16;            // this wave's 16 units
  const int uu   = u0 + quad * 4;     // units this thread activates
  const int sB   = blockIdx.x * 16;

  // ---- weights: BOTH layers per wave ----
  // L0: wW0[2g+f]=Whh0(g,f); wX0[g]=Wih0 x-frag (quad0 only)
  // L1: wI1[2g+f]=Wih1(g,f); wH1[2g+f]=Whh1(g,f)
  h8 wW0[8], wX0[4], wI1[8], wH1[8];
  f4 bias0[4], bias1[4];
#pragma unroll
  for (int g = 0; g < 4; ++g) {
    const float sc = (g == 2) ? K2F : K1F;
    const int r = g * 64 + u0 + col;
#pragma unroll
    for (int f = 0; f < 2; ++f) {
      wW0[2 * g + f] = load_w8s(Whh0 + r * 64 + f * 32 + quad * 8, sc);
      wI1[2 * g + f] = load_w8s(Wih1 + r * 64 + f * 32 + quad * 8, sc);
      wH1[2 * g + f] = load_w8s(Whh1 + r * 64 + f * 32 + quad * 8, sc);
    }
    h8 xw = {};
    if (quad == 0) {
#pragma unroll
      for (int j = 0; j < 4; ++j) xw[j] = (_Float16)(Wih0[r * 4 + j] * sc);
    }
    wX0[g] = xw;
#pragma unroll
    for (int j = 0; j < 4; ++j) {
      bias0[g][j] = (bih0[g * 64 + uu + j] + bhh0[g * 64 + uu + j]) * sc;
      bias1[g][j] = (bih1[g * 64 + uu + j] + bhh1[g * 64 + uu + j]) * sc;
    }
  }

  // ---- zero h rings ----
  for (int idx = tid; idx < SMEM_TOTAL / 4; idx += 256) ((int*)smem)[idx] = 0;
  __syncthreads();

  // ---- x prefetch registers (quad0 lanes) ----
  f4 xc = {};
  if (quad == 0)
    xc = *(const f4*)(x + ((size_t)(sB + col) * 168 + 0) * 4);

  float c0s[4] = {0.f, 0.f, 0.f, 0.f};
  float c1s[4] = {0.f, 0.f, 0.f, 0.f};
  float hl[4]  = {0.f, 0.f, 0.f, 0.f};    // final h2
  const int bo = col * ROWB + quad * 16;  // B-frag byte offset
  const int wo = col * ROWB + uu * 2;     // h-write byte offset (8B aligned)

  for (int k = 0; k <= 168; ++k) {
    const int kb = k & 1, kbn = kb ^ 1;
    const unsigned char* h0r = smem + H0_OFF + kbn * HBUF;  // h0(k-1)
    unsigned char*       h0w = smem + H0_OFF + kb  * HBUF;  // h0(k)
    const unsigned char* h1r = smem + H1_OFF + kb  * HBUF;  // h1(k-2)
    unsigned char*       h1w = smem + H1_OFF + kbn * HBUF;  // h1(k-1)

    // ---- shared ds_reads (4 x b128) ----
    h8 b0  = *(const h8*)(h0r + bo);         // h0(k-1) k 0..31
    h8 b1v = *(const h8*)(h0r + bo + 64);    // h0(k-1) k 32..63
    h8 q0  = *(const h8*)(h1r + bo);         // h1(k-2) k 0..31
    h8 q1  = *(const h8*)(h1r + bo + 64);    // h1(k-2) k 32..63
    h8 bx = {};
    if (quad == 0) {
#pragma unroll
      for (int j = 0; j < 4; ++j) bx[j] = (_Float16)xc[j];
    }
    // prefetch x(k+1) (used next iter; hidden under this iter's work)
    {
      const int kn = (k < 167) ? k + 1 : k;
      f4 xn = xc;
      if (quad == 0)
        xn = *(const f4*)(x + ((size_t)(sB + col) * 168 + kn) * 4);
      xc = xn;
    }

    // ---- 28 MFMAs, 8 chains (4 L0 depth-3, 4 L1 depth-4) ----
    f4 A[4], C[4];
#pragma unroll
    for (int g = 0; g < 4; ++g) A[g] = mfma16(wW0[2 * g], b0, bias0[g]);
#pragma unroll
    for (int g = 0; g < 4; ++g) C[g] = mfma16(wI1[2 * g], b0, bias1[g]);
#pragma unroll
    for (int g = 0; g < 4; ++g) A[g] = mfma16(wW0[2 * g + 1], b1v, A[g]);
#pragma unroll
    for (int g = 0; g < 4; ++g) C[g] = mfma16(wI1[2 * g + 1], b1v, C[g]);
#pragma unroll
    for (int g = 0; g < 4; ++g) A[g] = mfma16(wX0[g], bx, A[g]);
#pragma unroll
    for (int g = 0; g < 4; ++g) C[g] = mfma16(wH1[2 * g], q0, C[g]);
#pragma unroll
    for (int g = 0; g < 4; ++g) C[g] = mfma16(wH1[2 * g + 1], q1, C[g]);

    // ---- 8 independent acts (4 L0 + 4 L1) ----
    if (k < 168) {
      h4 hv;
#pragma unroll
      for (int a = 0; a < 4; ++a) {
        float ho;
        lstm_act_s(A[0][a], A[1][a], A[2][a], A[3][a], c0s[a], ho);
        hv[a] = (_Float16)ho;
      }
      *(h4*)(h0w + wo) = hv;     // h0(k)
    }
    if (k >= 1) {
      h4 hv;
#pragma unroll
      for (int a = 0; a < 4; ++a) {
        lstm_act_s(C[0][a], C[1][a], C[2][a], C[3][a], c1s[a], hl[a]);
        hv[a] = (_Float16)hl[a];
      }
      *(h4*)(h1w + wo) = hv;     // h1(k-1)
    }
    __syncthreads();
  }

  // ---------- MLP head (h rings dead; overlay) ----------
  float* fh = (float*)smem;              // [16][64] final h2, fp32
  {
    f4 hv; hv[0] = hl[0]; hv[1] = hl[1]; hv[2] = hl[2]; hv[3] = hl[3];
    *(f4*)(fh + col * 64 + uu) = hv;
  }
  __syncthreads();

  {
    const int u = tid & 63, g2 = tid >> 6;   // 4 grps x 4 samples
    const float* w1r = W1 + u * 64;
    float* zl = (float*)(smem + 4096);       // [16][64]
#pragma unroll
    for (int rep = 0; rep < 4; ++rep) {
      const int s2 = g2 + rep * 4;
      float za = b1[u];
      const float* f0 = fh + s2 * 64;
      for (int j = 0; j < 64; ++j) za += w1r[j] * f0[j];
      zl[s2 * 64 + u] = fmaxf(za, 0.f);
    }
  }
  __syncthreads();

  if (tid < 192) {
    const float* zl = (const float*)(smem + 4096);
    const int s2 = tid / 12, o = tid - s2 * 12;
    float a = b2[o];
    for (int j = 0; j < 64; ++j) a += W2[o * 64 + j] * zl[s2 * 64 + j];
    out[(sB + s2) * 12 + o] = a;
  }
}

extern "C" void kernel_launch(void* const* d_in, const int* in_sizes, int n_in,
                              void* d_out, int out_size, void* d_ws, size_t ws_size,
                              hipStream_t stream) {
  (void)in_sizes; (void)n_in; (void)d_ws; (void)ws_size; (void)out_size;
  const float* x    = (const float*)d_in[0];
  const float* Wih0 = (const float*)d_in[1];
  const float* Whh0 = (const float*)d_in[2];
  const float* bih0 = (const float*)d_in[3];
  const float* bhh0 = (const float*)d_in[4];
  const float* Wih1 = (const float*)d_in[5];
  const float* Whh1 = (const float*)d_in[6];
  const float* bih1 = (const float*)d_in[7];
  const float* bhh1 = (const float*)d_in[8];
  const float* W1   = (const float*)d_in[9];
  const float* b1   = (const float*)d_in[10];
  const float* W2   = (const float*)d_in[11];
  const float* b2   = (const float*)d_in[12];

  weather_lstm_mfma13<<<dim3(256), dim3(256), 0, stream>>>(
      x, Wih0, Whh0, bih0, bhh0, Wih1, Whh1, bih1, bhh1, W1, b1, W2, b2,
      (float*)d_out);
}